// Round 14
// baseline (800.604 us; speedup 1.0000x reference)
//
#include <hip/hip_runtime.h>
#include <math.h>

// Problem constants
#define BB 512
#define SS 64
#define DD 128
#define FF 256   // 2D
#define NSYM 128
#define STK 16
#define NDEPTH 8

typedef _Float16 half_t;
typedef __attribute__((ext_vector_type(4))) _Float16 half4;
typedef __attribute__((ext_vector_type(8))) _Float16 half8;
typedef __attribute__((ext_vector_type(4))) float f32x4;

// Workspace offsets (in floats)
#define Z_OFF      0ull                    // B*S*F      = 8388608
#define QKV_OFF    8388608ull              // WT32 + GT/WvT split planes (attn)
#define WVM_OFF    33554432ull             // Wv32m [e][c] = 65536
#define MV_OFF     35651584ull             // mv state B*256 = 131072
#define SIG_OFF    35782656ull             // sigma B = 512
#define ZF2_OFF    42082304ull             // B*256      = 131072
#define READ_OFF   42213376ull             // B*256      = 131072
#define PROBS_OFF  42344448ull             // B*128      = 65536
#define DELTA_OFF  42409984ull             // B*256      = 131072 (read + quant)
#define HALT_OFF   42541056ull             // B          = 512
#define PVAL_OFF   42541568ull             // B          = 512
#define WACT_OFF   42542080ull             // B          = 512
#define MAGP_OFF   42542592ull             // B*2        = 1024
#define CB2_OFF    42936832ull             // 128

// ---------------------------------------------------------------------------
// Combined transposed weight, fp32: WT32[col=h*256+c][e] = W_h[e][c]
__global__ void k_buildwt32(const float* __restrict__ wr, const float* __restrict__ wi,
                            float* __restrict__ WT32) {
    int idx = blockIdx.x * 256 + threadIdx.x;   // 196608 total, grid=768
    if (idx >= 768 * 256) return;
    int col = idx >> 8;
    int e   = idx & 255;
    int h   = col >> 8;
    int c   = col & 255;
    const float* Wr = wr + h * DD * DD;
    const float* Wi = wi + h * DD * DD;
    float v;
    if (c < DD) {
        v = (e < DD) ? Wr[c * DD + e] : -Wi[c * DD + (e - DD)];
    } else {
        int j = c - DD;
        v = (e < DD) ? Wi[j * DD + e] : Wr[j * DD + (e - DD)];
    }
    WT32[idx] = v;
}

// GT[n][e] = G[e][n] = sum_c Wq[e][c]*Wk[n][c], split to fp16 h/l (unscaled).
__global__ __launch_bounds__(256) void k_buildG(const float* __restrict__ WT32,
                                                half_t* __restrict__ GTh,
                                                half_t* __restrict__ GTl) {
    __shared__ float kcol[256];
    int n = blockIdx.x;
    int e = threadIdx.x;
    kcol[e] = WT32[65536 + e * 256 + n];   // Wk[n][c=e]
    __syncthreads();
    float s = 0.f;
    for (int c = 0; c < 256; ++c) s += kcol[c] * WT32[c * 256 + e];  // Wq[e][c]
    half_t h = (half_t)s;
    GTh[n * 256 + e] = h;
    GTl[n * 256 + e] = (half_t)(s - (float)h);
}

// Split the attn V-head columns (cols 512..767 of WT32) to fp16 h/l (transposed).
__global__ void k_splitWv(const float* __restrict__ WT32,
                          half_t* __restrict__ WvTh, half_t* __restrict__ WvTl) {
    int idx = blockIdx.x * 256 + threadIdx.x;   // 65536, grid 256
    float v = WT32[131072 + idx];   // WvT[n][e]
    half_t h = (half_t)v;
    WvTh[idx] = h;
    WvTl[idx] = (half_t)(v - (float)h);
}

// Mem-path V weight in [e][c] fp32 layout (c contiguous -> coalesced dots).
__global__ void k_buildWv32m(const float* __restrict__ wr, const float* __restrict__ wi,
                             float* __restrict__ Wv32m) {
    int idx = blockIdx.x * 256 + threadIdx.x;   // 65536, grid 256
    int e = idx >> 8;
    int c = idx & 255;
    const float* Wr = wr + 2 * DD * DD;   // V head
    const float* Wi = wi + 2 * DD * DD;
    float v;
    if (c < DD) {
        v = (e < DD) ? Wr[c * DD + e] : -Wi[c * DD + (e - DD)];
    } else {
        int j = c - DD;
        v = (e < DD) ? Wi[j * DD + e] : Wr[j * DD + (e - DD)];
    }
    Wv32m[idx] = v;
}

__global__ void k_cb2(const float* __restrict__ cb, float* __restrict__ cb2) {
    int n = threadIdx.x;   // 128 threads
    float s = 0.f;
    for (int c = 0; c < FF; ++c) { float v = cb[n * FF + c]; s += v * v; }
    cb2[n] = s;
}

__global__ __launch_bounds__(256) void k_init(const float* __restrict__ zr_in,
                                              const float* __restrict__ zi_in,
                                              float* __restrict__ z, float* __restrict__ mv,
                                              float* __restrict__ sigma,
                                              float* __restrict__ halt, float* __restrict__ acc,
                                              float* __restrict__ delta, float* __restrict__ wact) {
    size_t idx = (size_t)blockIdx.x * 256 + threadIdx.x;  // grid 32768 -> 8388608
    int c = (int)(idx & 255);
    size_t bs = idx >> 8;
    z[idx] = (c < DD) ? zr_in[bs * DD + c] : zi_in[bs * DD + (c - DD)];
    acc[idx] = 0.f;
    if (idx < 131072) { mv[idx] = 0.f; delta[idx] = 0.f; }
    if (idx < 512)   { halt[idx] = 0.f; wact[idx] = 0.f; sigma[idx] = 1.f; }
}

// ---------------------------------------------------------------------------
// Fused attention + stack step. 8 waves, 1 blk/CU.
// Attn: R13 body (S split over 8 waves, online-softmax merge).
// Tail: zf1 -> gates || zfWv dot -> sigma/mv recurrence -> read -> zf2/pval
//       -> mag sweep from the LDS-resident z1 (no global z re-read).
__global__ __launch_bounds__(512, 1) void k_attn8(
        float* __restrict__ z,
        const half_t* __restrict__ GTh, const half_t* __restrict__ GTl,
        const half_t* __restrict__ WvTh, const half_t* __restrict__ WvTl,
        const float* __restrict__ delta, const float* __restrict__ wact,
        float* __restrict__ acc,
        const float* __restrict__ Wv32m,
        const float* __restrict__ ctrl_w, const float* __restrict__ ctrl_b,
        const float* __restrict__ halt_w, const float* __restrict__ halt_b,
        float* __restrict__ sigma, float* __restrict__ mv,
        float* __restrict__ readv, float* __restrict__ zf2,
        float* __restrict__ pval, float* __restrict__ magpart) {
    __shared__ __align__(16) char smem[160768];
    half_t* Zh = (half_t*)smem;                    // 64 x 264 halves
    half_t* Zl = (half_t*)(smem + 33792);
    float*  Zf = (float*)smem;                     // alias: z1 [64][256] (after sync A)
    half_t* U0 = (half_t*)(smem + 67584);          // T[64][264] / VT[256][72]
    half_t* U1 = (half_t*)(smem + 104448);
    half_t* P0 = (half_t*)(smem + 141312);
    half_t* P1 = (half_t*)(smem + 150528);
    float* Smx = (float*)(smem + 159744);          // [4][2][16]
    float* Ssu = (float*)(smem + 160256);
    // stack-tail scratch aliases U0 (dead after phase O / sync A)
    float* zfS = (float*)(smem + 67584);           // 256
    float* zwS = (float*)(smem + 68608);           // 256
    float* rdS = (float*)(smem + 69632);           // 256
    float* redS= (float*)(smem + 70656);           // 24
    float* gS  = (float*)(smem + 71680);           // 3

    int b = blockIdx.x, tid = threadIdx.x;
    int w = tid >> 6, lane = tid & 63;
    int l15 = lane & 15, lq = lane >> 4;
    float* zb = z + (size_t)b * (SS * FF);
    float* accb = acc + (size_t)b * (SS * FF);
    float sigold = sigma[b];   // read early; written only by tid 0 at tail

    // ---- phase 0: x0 = z + 0.1*delta; deferred acc; split to LDS
    float wa = wact[b];
    f32x4 dv = *(const f32x4*)(delta + b * FF + lane * 4);
    bool doacc = (wa != 0.0f);
#pragma unroll
    for (int it = 0; it < 8; ++it) {
        int i = w * 8 + it;
        f32x4 zv = *(const f32x4*)(zb + (size_t)i * FF + lane * 4);
        f32x4 x0;
#pragma unroll
        for (int jj = 0; jj < 4; ++jj) x0[jj] = zv[jj] + 0.1f * dv[jj];
        if (doacc) {
            f32x4 av = *(const f32x4*)(accb + (size_t)i * FF + lane * 4);
#pragma unroll
            for (int jj = 0; jj < 4; ++jj) av[jj] += wa * x0[jj];
            *(f32x4*)(accb + (size_t)i * FF + lane * 4) = av;
        }
        half4 h4, l4;
#pragma unroll
        for (int jj = 0; jj < 4; ++jj) {
            half_t h = (half_t)x0[jj];
            h4[jj] = h; l4[jj] = (half_t)(x0[jj] - (float)h);
        }
        *(half4*)&Zh[i * 264 + lane * 4] = h4;
        *(half4*)&Zl[i * 264 + lane * 4] = l4;
    }
    __syncthreads();   // sync 1: Z staged

    // ---- phase T: T = x0 @ G, wave w owns 32-col band.
    {
        f32x4 tac[4][2];
#pragma unroll
        for (int mt = 0; mt < 4; ++mt)
#pragma unroll
            for (int nt = 0; nt < 2; ++nt) tac[mt][nt] = (f32x4){0.f, 0.f, 0.f, 0.f};
        __builtin_amdgcn_s_setprio(1);
#pragma unroll 2
        for (int kt = 0; kt < 8; ++kt) {
            int kc = kt * 32 + lq * 8;
            half8 ah[4], al[4], gh[2], gl[2];
#pragma unroll
            for (int mt = 0; mt < 4; ++mt) {
                int ro = (mt * 16 + l15) * 264 + kc;
                ah[mt] = *(const half8*)&Zh[ro];
                al[mt] = *(const half8*)&Zl[ro];
            }
#pragma unroll
            for (int nt = 0; nt < 2; ++nt) {
                size_t go = (size_t)(w * 32 + nt * 16 + l15) * 256 + kc;
                gh[nt] = *(const half8*)(GTh + go);
                gl[nt] = *(const half8*)(GTl + go);
            }
#pragma unroll
            for (int mt = 0; mt < 4; ++mt)
#pragma unroll
                for (int nt = 0; nt < 2; ++nt) {
                    tac[mt][nt] = __builtin_amdgcn_mfma_f32_16x16x32_f16(ah[mt], gh[nt], tac[mt][nt], 0, 0, 0);
                    tac[mt][nt] = __builtin_amdgcn_mfma_f32_16x16x32_f16(ah[mt], gl[nt], tac[mt][nt], 0, 0, 0);
                    tac[mt][nt] = __builtin_amdgcn_mfma_f32_16x16x32_f16(al[mt], gh[nt], tac[mt][nt], 0, 0, 0);
                }
        }
        __builtin_amdgcn_s_setprio(0);
        const float scale = 0.08838834764831845f;
#pragma unroll
        for (int mt = 0; mt < 4; ++mt)
#pragma unroll
            for (int nt = 0; nt < 2; ++nt)
#pragma unroll
                for (int r = 0; r < 4; ++r) {
                    int m = mt * 16 + lq * 4 + r;
                    int n = w * 32 + nt * 16 + l15;
                    float v = tac[mt][nt][r] * scale;
                    half_t h = (half_t)v;
                    U0[m * 264 + n] = h;
                    U1[m * 264 + n] = (half_t)(v - (float)h);
                }
    }
    __syncthreads();   // sync 2: T ready

    // ---- phase B: all 8 waves: S half (j-split) -> partial stats; then V band.
    int qb = w & 3;    // query band
    int jh = w >> 2;   // j half
    float sv[2][4];
    {
        f32x4 sac[2];
        sac[0] = (f32x4){0.f, 0.f, 0.f, 0.f};
        sac[1] = (f32x4){0.f, 0.f, 0.f, 0.f};
        __builtin_amdgcn_s_setprio(1);
#pragma unroll 2
        for (int kt = 0; kt < 8; ++kt) {
            int kc = kt * 32 + lq * 8;
            int to = (qb * 16 + l15) * 264 + kc;
            half8 bh = *(const half8*)&U0[to];
            half8 bl = *(const half8*)&U1[to];
            half8 ah[2], al[2];
#pragma unroll
            for (int jt = 0; jt < 2; ++jt) {
                int ro = ((jh * 2 + jt) * 16 + l15) * 264 + kc;
                ah[jt] = *(const half8*)&Zh[ro];
                al[jt] = *(const half8*)&Zl[ro];
            }
#pragma unroll
            for (int jt = 0; jt < 2; ++jt) {
                sac[jt] = __builtin_amdgcn_mfma_f32_16x16x32_f16(ah[jt], bh, sac[jt], 0, 0, 0);
                sac[jt] = __builtin_amdgcn_mfma_f32_16x16x32_f16(ah[jt], bl, sac[jt], 0, 0, 0);
                sac[jt] = __builtin_amdgcn_mfma_f32_16x16x32_f16(al[jt], bh, sac[jt], 0, 0, 0);
            }
        }
        __builtin_amdgcn_s_setprio(0);
        float mxh = -1e30f;
#pragma unroll
        for (int jt = 0; jt < 2; ++jt)
#pragma unroll
            for (int r = 0; r < 4; ++r) { sv[jt][r] = sac[jt][r]; mxh = fmaxf(mxh, sv[jt][r]); }
        mxh = fmaxf(mxh, __shfl_xor(mxh, 16));
        mxh = fmaxf(mxh, __shfl_xor(mxh, 32));
        float sumh = 0.f;
#pragma unroll
        for (int jt = 0; jt < 2; ++jt)
#pragma unroll
            for (int r = 0; r < 4; ++r) { float e = expf(sv[jt][r] - mxh); sv[jt][r] = e; sumh += e; }
        sumh += __shfl_xor(sumh, 16);
        sumh += __shfl_xor(sumh, 32);
        if (lq == 0) { Smx[(qb * 2 + jh) * 16 + l15] = mxh; Ssu[(qb * 2 + jh) * 16 + l15] = sumh; }
    }

    // V band (all waves, 32 cols each)
    f32x4 vac[4][2];
#pragma unroll
    for (int mt = 0; mt < 4; ++mt)
#pragma unroll
        for (int nt = 0; nt < 2; ++nt) vac[mt][nt] = (f32x4){0.f, 0.f, 0.f, 0.f};
    __builtin_amdgcn_s_setprio(1);
#pragma unroll 2
    for (int kt = 0; kt < 8; ++kt) {
        int kc = kt * 32 + lq * 8;
        half8 ah[4], al[4], gh[2], gl[2];
#pragma unroll
        for (int mt = 0; mt < 4; ++mt) {
            int ro = (mt * 16 + l15) * 264 + kc;
            ah[mt] = *(const half8*)&Zh[ro];
            al[mt] = *(const half8*)&Zl[ro];
        }
#pragma unroll
        for (int nt = 0; nt < 2; ++nt) {
            size_t go = (size_t)(w * 32 + nt * 16 + l15) * 256 + kc;
            gh[nt] = *(const half8*)(WvTh + go);
            gl[nt] = *(const half8*)(WvTl + go);
        }
#pragma unroll
        for (int mt = 0; mt < 4; ++mt)
#pragma unroll
            for (int nt = 0; nt < 2; ++nt) {
                vac[mt][nt] = __builtin_amdgcn_mfma_f32_16x16x32_f16(ah[mt], gh[nt], vac[mt][nt], 0, 0, 0);
                vac[mt][nt] = __builtin_amdgcn_mfma_f32_16x16x32_f16(ah[mt], gl[nt], vac[mt][nt], 0, 0, 0);
                vac[mt][nt] = __builtin_amdgcn_mfma_f32_16x16x32_f16(al[mt], gh[nt], vac[mt][nt], 0, 0, 0);
            }
    }
    __builtin_amdgcn_s_setprio(0);
    __syncthreads();   // sync 3: S+T reads done, stats visible

    // finalize softmax (online merge) + write P for this wave's j half
    {
        float mx0 = Smx[(qb * 2 + 0) * 16 + l15], mx1 = Smx[(qb * 2 + 1) * 16 + l15];
        float gmx = fmaxf(mx0, mx1);
        float ssum = Ssu[(qb * 2 + 0) * 16 + l15] * expf(mx0 - gmx)
                   + Ssu[(qb * 2 + 1) * 16 + l15] * expf(mx1 - gmx);
        float pscale = expf(((jh == 0) ? mx0 : mx1) - gmx) / ssum;
#pragma unroll
        for (int jt = 0; jt < 2; ++jt) {
            half4 h4, l4;
#pragma unroll
            for (int r = 0; r < 4; ++r) {
                float pv = sv[jt][r] * pscale;
                half_t hh = (half_t)pv;
                h4[r] = hh;
                l4[r] = (half_t)(pv - (float)hh);
            }
            int po = l15 * 72 + (jh * 2 + jt) * 16 + lq * 4;
            *(half4*)&P0[qb * 1152 + po] = h4;
            *(half4*)&P1[qb * 1152 + po] = l4;
        }
    }

    // VT write
#pragma unroll
    for (int mt = 0; mt < 4; ++mt)
#pragma unroll
        for (int nt = 0; nt < 2; ++nt) {
            int n = w * 32 + nt * 16 + l15;
            int m0 = mt * 16 + lq * 4;
            half4 h4, l4;
#pragma unroll
            for (int r = 0; r < 4; ++r) {
                float v = vac[mt][nt][r];
                half_t h = (half_t)v;
                h4[r] = h; l4[r] = (half_t)(v - (float)h);
            }
            *(half4*)&U0[n * 72 + m0] = h4;
            *(half4*)&U1[n * 72 + m0] = l4;
        }
    __syncthreads();   // sync 4: VT + P visible

    // ---- phase O
    f32x4 oc[4][2];
#pragma unroll
    for (int mt = 0; mt < 4; ++mt)
#pragma unroll
        for (int nt = 0; nt < 2; ++nt) oc[mt][nt] = (f32x4){0.f, 0.f, 0.f, 0.f};
    __builtin_amdgcn_s_setprio(1);
#pragma unroll
    for (int kt = 0; kt < 2; ++kt) {
        half8 pah[4], pal[4];
#pragma unroll
        for (int mt = 0; mt < 4; ++mt) {
            int po = l15 * 72 + kt * 32 + lq * 8;
            pah[mt] = *(const half8*)&P0[mt * 1152 + po];
            pal[mt] = *(const half8*)&P1[mt * 1152 + po];
        }
#pragma unroll
        for (int nt = 0; nt < 2; ++nt) {
            int n = w * 32 + nt * 16 + l15;
            half8 vbh = *(const half8*)&U0[n * 72 + kt * 32 + lq * 8];
            half8 vbl = *(const half8*)&U1[n * 72 + kt * 32 + lq * 8];
#pragma unroll
            for (int mt = 0; mt < 4; ++mt) {
                oc[mt][nt] = __builtin_amdgcn_mfma_f32_16x16x32_f16(pah[mt], vbh, oc[mt][nt], 0, 0, 0);
                oc[mt][nt] = __builtin_amdgcn_mfma_f32_16x16x32_f16(pah[mt], vbl, oc[mt][nt], 0, 0, 0);
                oc[mt][nt] = __builtin_amdgcn_mfma_f32_16x16x32_f16(pal[mt], vbh, oc[mt][nt], 0, 0, 0);
            }
        }
    }
    __builtin_amdgcn_s_setprio(0);

    // ---- epilogue pass 1: z1 = O + 0.1*x0 (into oc regs), zf1 partials, global write
    float zfs[2] = {0.f, 0.f};
#pragma unroll
    for (int mt = 0; mt < 4; ++mt)
#pragma unroll
        for (int nt = 0; nt < 2; ++nt)
#pragma unroll
            for (int r = 0; r < 4; ++r) {
                int i = mt * 16 + lq * 4 + r;
                int c = w * 32 + nt * 16 + l15;
                int zo = i * 264 + c;
                float x0 = (float)Zh[zo] + (float)Zl[zo];
                float z1 = oc[mt][nt][r] + 0.1f * x0;
                oc[mt][nt][r] = z1;
                zb[(size_t)i * FF + c] = z1;
                zfs[nt] += z1;
            }
#pragma unroll
    for (int nt = 0; nt < 2; ++nt) {
        zfs[nt] += __shfl_xor(zfs[nt], 16);
        zfs[nt] += __shfl_xor(zfs[nt], 32);
    }
    __syncthreads();   // sync A: all Zh/Zl + U/P reads complete

    // ---- pass 2: stage z1 into Zf (alias), publish zf1 col-means
#pragma unroll
    for (int mt = 0; mt < 4; ++mt)
#pragma unroll
        for (int nt = 0; nt < 2; ++nt)
#pragma unroll
            for (int r = 0; r < 4; ++r) {
                int i = mt * 16 + lq * 4 + r;
                int c = w * 32 + nt * 16 + l15;
                Zf[i * 256 + c] = oc[mt][nt][r];
            }
    if (lq == 0) {
#pragma unroll
        for (int nt = 0; nt < 2; ++nt)
            zfS[w * 32 + nt * 16 + l15] = zfs[nt] * (1.f / 64.f);
    }
    __syncthreads();   // sync B: Zf + zfS ready

    // ---- gates (waves 0-2) || zfWv dot (waves 4-7)
    if (w < 3) {
        float s = 0.f;
#pragma unroll
        for (int q = 0; q < 4; ++q) {
            int c = lane + 64 * q;
            s += zfS[c] * ctrl_w[c * 3 + w];
        }
#pragma unroll
        for (int off = 1; off < 64; off <<= 1) s += __shfl_xor(s, off);
        if (lane == 0) gS[w] = 1.f / (1.f + expf(-(s + ctrl_b[w])));
    } else if (w >= 4) {
        int c = (w - 4) * 64 + lane;
        float s = 0.f;
#pragma unroll 8
        for (int e = 0; e < 256; ++e) s += Wv32m[e * 256 + c] * zfS[e];
        zwS[c] = s;
    }
    __syncthreads();   // sync C: gates + zw ready

    // ---- stack recurrence + read + zf2 (threads 0-255)
    float z2 = 0.f;
    {
        float tot = gS[0] + gS[1] + gS[2] + 1e-6f;
        float push = gS[0] / tot, pop = gS[1] / tot, stay = gS[2] / tot;
        float signew = sigold * (push + pop + stay);
        if (tid == 0) sigma[b] = signew;
        if (tid < 256) {
            float m2v = mv[b * FF + tid] * (1.f - push) + push * zwS[tid];
            mv[b * FF + tid] = m2v;
            float a = signew * m2v;
            rdS[tid] = a;
            readv[b * FF + tid] = a;
            z2 = zfS[tid] + 0.1f * a;
            zf2[b * FF + tid] = z2;
        }
    }
    // pval partial (wave-level)
    {
        float hp = (tid < 256) ? z2 * halt_w[tid] : 0.f;
#pragma unroll
        for (int off = 1; off < 64; off <<= 1) hp += __shfl_xor(hp, off);
        if (lane == 0) redS[w] = hp;
    }
    __syncthreads();   // sync D: rdS + pval partials visible
    if (tid == 0) {
        float s = redS[0] + redS[1] + redS[2] + redS[3] + redS[4] + redS[5] + redS[6] + redS[7];
        pval[b] = 1.f / (1.f + expf(-(s + halt_b[0])));
    }

    // ---- mag sweep from LDS z1
    {
        int d = tid & 127, seg = tid >> 7;
        float rr = 0.1f * rdS[d];
        float ri = 0.1f * rdS[DD + d];
        float ms = 0.f, msq = 0.f;
#pragma unroll 4
        for (int r16 = 0; r16 < 16; ++r16) {
            int s = seg * 16 + r16;
            float zr = Zf[s * 256 + d] + rr;
            float zi = Zf[s * 256 + DD + d] + ri;
            float m2 = zr * zr + zi * zi;
            ms += sqrtf(m2); msq += m2;
        }
#pragma unroll
        for (int off = 1; off < 64; off <<= 1) {
            ms  += __shfl_xor(ms, off);
            msq += __shfl_xor(msq, off);
        }
        if (lane == 0) { redS[8 + w] = ms; redS[16 + w] = msq; }
    }
    __syncthreads();   // sync E
    if (tid == 0) {
        float tms  = redS[8]  + redS[9]  + redS[10] + redS[11] + redS[12] + redS[13] + redS[14] + redS[15];
        float tmsq = redS[16] + redS[17] + redS[18] + redS[19] + redS[20] + redS[21] + redS[22] + redS[23];
        magpart[2 * b] = tms;
        magpart[2 * b + 1] = tmsq;
    }
}

// ---------------------------------------------------------------------------
// Lean VQ kernel; when last!=0 also performs the final ACT accumulation.
__global__ __launch_bounds__(256) void k_vq2(
        const float* __restrict__ zf2g, const float* __restrict__ readv,
        float* __restrict__ probs, float* __restrict__ halt,
        const float* __restrict__ pvalg, const float* __restrict__ magp,
        const float* __restrict__ cb, const float* __restrict__ cb2,
        const float* __restrict__ adj,
        float* __restrict__ delta, float* __restrict__ wact,
        const float* __restrict__ z, float* __restrict__ acc,
        int t, int last) {
    __shared__ float zf[256];
    __shared__ float pr[128];
    __shared__ float upred[8];
    __shared__ float zzred[4];
    __shared__ float mxred[4];
    __shared__ float sered[4];
    __shared__ float waS[1];

    int b = blockIdx.x, tid = threadIdx.x;
    int w = tid >> 6, lane = tid & 63;

    zf[tid] = zf2g[b * FF + tid];

    float up = 0.f;
    if (t > 0) {
        f32x4 mv4 = *(const f32x4*)(magp + tid * 4);
        float pa = mv4[0] + mv4[2];
        float pb = mv4[1] + mv4[3];
#pragma unroll
        for (int off = 1; off < 64; off <<= 1) {
            pa += __shfl_xor(pa, off);
            pb += __shfl_xor(pb, off);
        }
        if (lane == 0) { upred[w * 2] = pa; upred[w * 2 + 1] = pb; }
    }
    __syncthreads();
    if (t > 0) {
        float tms  = upred[0] + upred[2] + upred[4] + upred[6];
        float tmsq = upred[1] + upred[3] + upred[5] + upred[7];
        const float N = 4194304.f;   // B*S*D
        float mean = tms / N;
        float var = tmsq / N - mean * mean;
        float x = var / (1.f + 1e-6f);
        up = (x > 20.f) ? x : log1pf(expf(x));
    }

    {
        float part = zf[tid] * zf[tid];
#pragma unroll
        for (int off = 1; off < 64; off <<= 1) part += __shfl_xor(part, off);
        if (lane == 0) zzred[w] = part;
    }
    __syncthreads();
    float zz = zzred[0] + zzred[1] + zzred[2] + zzred[3];

    int n = tid >> 1, half = tid & 1;
    float dacc = 0.f;
    {
        const float* cbn = cb + n * FF + half * 128;
        const float* zfp = zf + half * 128;
#pragma unroll 8
        for (int c2 = 0; c2 < 128; c2 += 4) {
            f32x4 cv = *(const f32x4*)(cbn + c2);
            dacc += cv[0] * zfp[c2] + cv[1] * zfp[c2 + 1] + cv[2] * zfp[c2 + 2] + cv[3] * zfp[c2 + 3];
        }
        dacc += __shfl_xor(dacc, 1);
    }
    float gacc = 0.f;
    if (t > 0) {
        const float* pp = probs + b * NSYM;
        for (int k = half * 64; k < half * 64 + 64; ++k)
            gacc += pp[k] * adj[k * NSYM + n];
        gacc += __shfl_xor(gacc, 1);
    }

    float dist = (zz + cb2[n] - 2.f * dacc) * (1.f / 256.f);
    float dtot = dist;
    if (t > 0) dtot = dist - 0.01f * up * (1.f / (1.f + expf(-gacc)));
    float vval = -dtot;   // TEMP = 1

    {
        float m = vval;
#pragma unroll
        for (int off = 1; off < 64; off <<= 1) m = fmaxf(m, __shfl_xor(m, off));
        if (lane == 0) mxred[w] = m;
    }
    __syncthreads();
    float mx = fmaxf(fmaxf(mxred[0], mxred[1]), fmaxf(mxred[2], mxred[3]));

    float e = expf(vval - mx);
    {
        float s = (half == 0) ? e : 0.f;
#pragma unroll
        for (int off = 1; off < 64; off <<= 1) s += __shfl_xor(s, off);
        if (lane == 0) sered[w] = s;
    }
    __syncthreads();
    float se = sered[0] + sered[1] + sered[2] + sered[3];
    float psm = e / se;
    if (half == 0) {
        pr[n] = psm;
        probs[b * NSYM + n] = psm;
    }
    __syncthreads();

    float q = 0.f;
#pragma unroll 4
    for (int k = 0; k < NSYM; ++k) q += pr[k] * cb[k * FF + tid];
    float dltc = readv[b * FF + tid] + q;
    delta[b * FF + tid] = dltc;

    if (tid == 0) {
        float h = halt[b], p = pvalg[b];
        float running = (h < 0.99f) ? 1.f : 0.f;
        float w2 = (((h + p * running) >= 0.99f) ? (1.f - h) : p) * running;
        halt[b] = h + w2;
        wact[b] = w2;
        waS[0] = w2;
    }

    if (last) {
        __syncthreads();
        float wa = waS[0];
        if (wa != 0.0f) {
            const float* zb = z + (size_t)b * (SS * FF);
            float* ab = acc + (size_t)b * (SS * FF);
            for (int s = 0; s < SS; ++s)
                ab[s * FF + tid] += wa * (zb[s * FF + tid] + 0.1f * dltc);
        }
    }
}

// ---------------------------------------------------------------------------
extern "C" void kernel_launch(void* const* d_in, const int* in_sizes, int n_in,
                              void* d_out, int out_size, void* d_ws, size_t ws_size,
                              hipStream_t stream) {
    const float* z_real  = (const float*)d_in[0];
    const float* z_imag  = (const float*)d_in[1];
    const float* attn_wr = (const float*)d_in[2];
    const float* attn_wi = (const float*)d_in[3];
    const float* mem_wr  = (const float*)d_in[4];
    const float* mem_wi  = (const float*)d_in[5];
    const float* ctrl_w  = (const float*)d_in[6];
    const float* ctrl_b  = (const float*)d_in[7];
    const float* halt_w  = (const float*)d_in[8];
    const float* halt_b  = (const float*)d_in[9];
    const float* codebook  = (const float*)d_in[10];
    const float* adjacency = (const float*)d_in[11];

    float* ws = (float*)d_ws;
    float* z      = ws + Z_OFF;
    float* WT32   = ws + QKV_OFF;
    half_t* GTh   = (half_t*)(ws + QKV_OFF + 196608);
    half_t* GTl   = GTh + 65536;
    half_t* WvTh  = GTl + 65536;
    half_t* WvTl  = WvTh + 65536;
    float* Wv32m  = ws + WVM_OFF;
    float* mv     = ws + MV_OFF;
    float* sigma  = ws + SIG_OFF;
    float* zf2    = ws + ZF2_OFF;
    float* readv  = ws + READ_OFF;
    float* probs  = ws + PROBS_OFF;
    float* delta  = ws + DELTA_OFF;
    float* halt   = ws + HALT_OFF;
    float* pval   = ws + PVAL_OFF;
    float* wact   = ws + WACT_OFF;
    float* magp   = ws + MAGP_OFF;
    float* cb2    = ws + CB2_OFF;
    float* acc    = (float*)d_out;

    k_buildwt32<<<768, 256, 0, stream>>>(attn_wr, attn_wi, WT32);
    k_buildG<<<256, 256, 0, stream>>>(WT32, GTh, GTl);
    k_splitWv<<<256, 256, 0, stream>>>(WT32, WvTh, WvTl);
    k_buildWv32m<<<256, 256, 0, stream>>>(mem_wr, mem_wi, Wv32m);
    k_cb2<<<1, 128, 0, stream>>>(codebook, cb2);
    k_init<<<32768, 256, 0, stream>>>(z_real, z_imag, z, mv, sigma, halt, acc,
                                      delta, wact);

    for (int t = 0; t < NDEPTH; ++t) {
        k_attn8<<<BB, 512, 0, stream>>>(z, GTh, GTl, WvTh, WvTl, delta, wact, acc,
                                        Wv32m, ctrl_w, ctrl_b, halt_w, halt_b,
                                        sigma, mv, readv, zf2, pval, magp);
        k_vq2<<<BB, 256, 0, stream>>>(zf2, readv, probs, halt, pval, magp,
                                      codebook, cb2, adjacency, delta, wact,
                                      z, acc, t, (t == NDEPTH - 1) ? 1 : 0);
    }
}

// Round 15
// 786.304 us; speedup vs baseline: 1.0182x; 1.0182x over previous
//
#include <hip/hip_runtime.h>
#include <math.h>

// Problem constants
#define BB 512
#define SS 64
#define DD 128
#define FF 256   // 2D
#define NSYM 128
#define STK 16
#define NDEPTH 8

typedef _Float16 half_t;
typedef __attribute__((ext_vector_type(4))) _Float16 half4;
typedef __attribute__((ext_vector_type(8))) _Float16 half8;
typedef __attribute__((ext_vector_type(4))) float f32x4;

// Workspace offsets (in floats)
#define Z_OFF      0ull                    // B*S*F      = 8388608
#define QKV_OFF    8388608ull              // WT32 + GT/WvT split planes (attn)
#define WVM_OFF    33554432ull             // Wv32m [e][c] = 65536
#define MV_OFF     35651584ull             // mv state B*256 = 131072
#define SIG_OFF    35782656ull             // sigma B = 512
#define ZF1_OFF    41951232ull             // B*256      = 131072
#define ZF2_OFF    42082304ull             // B*256      = 131072
#define READ_OFF   42213376ull             // B*256      = 131072
#define PROBS_OFF  42344448ull             // B*128      = 65536
#define DELTA_OFF  42409984ull             // B*256      = 131072 (read + quant)
#define HALT_OFF   42541056ull             // B          = 512
#define PVAL_OFF   42541568ull             // B          = 512
#define WACT_OFF   42542080ull             // B          = 512
#define MAGP_OFF   42542592ull             // B*2        = 1024
#define CB2_OFF    42936832ull             // 128

// ---------------------------------------------------------------------------
// Combined transposed weight, fp32: WT32[col=h*256+c][e] = W_h[e][c]
__global__ void k_buildwt32(const float* __restrict__ wr, const float* __restrict__ wi,
                            float* __restrict__ WT32) {
    int idx = blockIdx.x * 256 + threadIdx.x;   // 196608 total, grid=768
    if (idx >= 768 * 256) return;
    int col = idx >> 8;
    int e   = idx & 255;
    int h   = col >> 8;
    int c   = col & 255;
    const float* Wr = wr + h * DD * DD;
    const float* Wi = wi + h * DD * DD;
    float v;
    if (c < DD) {
        v = (e < DD) ? Wr[c * DD + e] : -Wi[c * DD + (e - DD)];
    } else {
        int j = c - DD;
        v = (e < DD) ? Wi[j * DD + e] : Wr[j * DD + (e - DD)];
    }
    WT32[idx] = v;
}

// GT[n][e] = G[e][n] = sum_c Wq[e][c]*Wk[n][c], split to fp16 h/l (unscaled).
__global__ __launch_bounds__(256) void k_buildG(const float* __restrict__ WT32,
                                                half_t* __restrict__ GTh,
                                                half_t* __restrict__ GTl) {
    __shared__ float kcol[256];
    int n = blockIdx.x;
    int e = threadIdx.x;
    kcol[e] = WT32[65536 + e * 256 + n];   // Wk[n][c=e]
    __syncthreads();
    float s = 0.f;
    for (int c = 0; c < 256; ++c) s += kcol[c] * WT32[c * 256 + e];  // Wq[e][c]
    half_t h = (half_t)s;
    GTh[n * 256 + e] = h;
    GTl[n * 256 + e] = (half_t)(s - (float)h);
}

// Split the attn V-head columns (cols 512..767 of WT32) to fp16 h/l (transposed).
__global__ void k_splitWv(const float* __restrict__ WT32,
                          half_t* __restrict__ WvTh, half_t* __restrict__ WvTl) {
    int idx = blockIdx.x * 256 + threadIdx.x;   // 65536, grid 256
    float v = WT32[131072 + idx];   // WvT[n][e]
    half_t h = (half_t)v;
    WvTh[idx] = h;
    WvTl[idx] = (half_t)(v - (float)h);
}

// Mem-path V weight in [e][c] fp32 layout (c contiguous -> coalesced dots).
__global__ void k_buildWv32m(const float* __restrict__ wr, const float* __restrict__ wi,
                             float* __restrict__ Wv32m) {
    int idx = blockIdx.x * 256 + threadIdx.x;   // 65536, grid 256
    int e = idx >> 8;
    int c = idx & 255;
    const float* Wr = wr + 2 * DD * DD;   // V head
    const float* Wi = wi + 2 * DD * DD;
    float v;
    if (c < DD) {
        v = (e < DD) ? Wr[c * DD + e] : -Wi[c * DD + (e - DD)];
    } else {
        int j = c - DD;
        v = (e < DD) ? Wi[j * DD + e] : Wr[j * DD + (e - DD)];
    }
    Wv32m[idx] = v;
}

__global__ void k_cb2(const float* __restrict__ cb, float* __restrict__ cb2) {
    int n = threadIdx.x;   // 128 threads
    float s = 0.f;
    for (int c = 0; c < FF; ++c) { float v = cb[n * FF + c]; s += v * v; }
    cb2[n] = s;
}

__global__ __launch_bounds__(256) void k_init(const float* __restrict__ zr_in,
                                              const float* __restrict__ zi_in,
                                              float* __restrict__ z, float* __restrict__ mv,
                                              float* __restrict__ sigma,
                                              float* __restrict__ halt, float* __restrict__ acc,
                                              float* __restrict__ delta, float* __restrict__ wact) {
    size_t idx = (size_t)blockIdx.x * 256 + threadIdx.x;  // grid 32768 -> 8388608
    int c = (int)(idx & 255);
    size_t bs = idx >> 8;
    z[idx] = (c < DD) ? zr_in[bs * DD + c] : zi_in[bs * DD + (c - DD)];
    acc[idx] = 0.f;
    if (idx < 131072) { mv[idx] = 0.f; delta[idx] = 0.f; }
    if (idx < 512)   { halt[idx] = 0.f; wact[idx] = 0.f; sigma[idx] = 1.f; }
}

// ---------------------------------------------------------------------------
// Fused attention step. 8 waves, 1 blk/CU. (R13 body; T/V loops unroll 4)
__global__ __launch_bounds__(512, 1) void k_attn8(
        float* __restrict__ z,
        const half_t* __restrict__ GTh, const half_t* __restrict__ GTl,
        const half_t* __restrict__ WvTh, const half_t* __restrict__ WvTl,
        const float* __restrict__ delta, const float* __restrict__ wact,
        float* __restrict__ acc, float* __restrict__ zf1g) {
    __shared__ half_t Zh[16896];         // 64 x 264, 33 KB
    __shared__ half_t Zl[16896];
    __shared__ half_t Ubuf[2][18432];    // union: T[64][264] / VT[256][72]
    __shared__ half_t Pbuf[2][4][1152];
    __shared__ float Smx[4][2][16];      // per-query partial softmax stats
    __shared__ float Ssum[4][2][16];

    int b = blockIdx.x, tid = threadIdx.x;
    int w = tid >> 6, lane = tid & 63;
    int l15 = lane & 15, lq = lane >> 4;
    float* zb = z + (size_t)b * (SS * FF);
    float* accb = acc + (size_t)b * (SS * FF);

    // ---- phase 0: x0 = z + 0.1*delta; deferred acc; split to LDS
    float wa = wact[b];
    f32x4 dv = *(const f32x4*)(delta + b * FF + lane * 4);
    bool doacc = (wa != 0.0f);
#pragma unroll
    for (int it = 0; it < 8; ++it) {
        int i = w * 8 + it;
        f32x4 zv = *(const f32x4*)(zb + (size_t)i * FF + lane * 4);
        f32x4 x0;
#pragma unroll
        for (int jj = 0; jj < 4; ++jj) x0[jj] = zv[jj] + 0.1f * dv[jj];
        if (doacc) {
            f32x4 av = *(const f32x4*)(accb + (size_t)i * FF + lane * 4);
#pragma unroll
            for (int jj = 0; jj < 4; ++jj) av[jj] += wa * x0[jj];
            *(f32x4*)(accb + (size_t)i * FF + lane * 4) = av;
        }
        half4 h4, l4;
#pragma unroll
        for (int jj = 0; jj < 4; ++jj) {
            half_t h = (half_t)x0[jj];
            h4[jj] = h; l4[jj] = (half_t)(x0[jj] - (float)h);
        }
        *(half4*)&Zh[i * 264 + lane * 4] = h4;
        *(half4*)&Zl[i * 264 + lane * 4] = l4;
    }
    __syncthreads();   // sync 1: Z staged

    // ---- phase T: T = x0 @ G, wave w owns 32-col band.
    {
        f32x4 tac[4][2];
#pragma unroll
        for (int mt = 0; mt < 4; ++mt)
#pragma unroll
            for (int nt = 0; nt < 2; ++nt) tac[mt][nt] = (f32x4){0.f, 0.f, 0.f, 0.f};
        __builtin_amdgcn_s_setprio(1);
#pragma unroll 4
        for (int kt = 0; kt < 8; ++kt) {
            int kc = kt * 32 + lq * 8;
            half8 ah[4], al[4], gh[2], gl[2];
#pragma unroll
            for (int mt = 0; mt < 4; ++mt) {
                int ro = (mt * 16 + l15) * 264 + kc;
                ah[mt] = *(const half8*)&Zh[ro];
                al[mt] = *(const half8*)&Zl[ro];
            }
#pragma unroll
            for (int nt = 0; nt < 2; ++nt) {
                size_t go = (size_t)(w * 32 + nt * 16 + l15) * 256 + kc;
                gh[nt] = *(const half8*)(GTh + go);
                gl[nt] = *(const half8*)(GTl + go);
            }
#pragma unroll
            for (int mt = 0; mt < 4; ++mt)
#pragma unroll
                for (int nt = 0; nt < 2; ++nt) {
                    tac[mt][nt] = __builtin_amdgcn_mfma_f32_16x16x32_f16(ah[mt], gh[nt], tac[mt][nt], 0, 0, 0);
                    tac[mt][nt] = __builtin_amdgcn_mfma_f32_16x16x32_f16(ah[mt], gl[nt], tac[mt][nt], 0, 0, 0);
                    tac[mt][nt] = __builtin_amdgcn_mfma_f32_16x16x32_f16(al[mt], gh[nt], tac[mt][nt], 0, 0, 0);
                }
        }
        __builtin_amdgcn_s_setprio(0);
        const float scale = 0.08838834764831845f;
#pragma unroll
        for (int mt = 0; mt < 4; ++mt)
#pragma unroll
            for (int nt = 0; nt < 2; ++nt)
#pragma unroll
                for (int r = 0; r < 4; ++r) {
                    int m = mt * 16 + lq * 4 + r;
                    int n = w * 32 + nt * 16 + l15;
                    float v = tac[mt][nt][r] * scale;
                    half_t h = (half_t)v;
                    Ubuf[0][m * 264 + n] = h;
                    Ubuf[1][m * 264 + n] = (half_t)(v - (float)h);
                }
    }
    __syncthreads();   // sync 2: T ready

    // ---- phase B: all 8 waves: S half (48 MFMA) -> partial stats; then V band.
    int qb = w & 3;    // query band
    int jh = w >> 2;   // j half
    float sv[2][4];
    {
        f32x4 sac[2];
        sac[0] = (f32x4){0.f, 0.f, 0.f, 0.f};
        sac[1] = (f32x4){0.f, 0.f, 0.f, 0.f};
        __builtin_amdgcn_s_setprio(1);
#pragma unroll 2
        for (int kt = 0; kt < 8; ++kt) {
            int kc = kt * 32 + lq * 8;
            int to = (qb * 16 + l15) * 264 + kc;
            half8 bh = *(const half8*)&Ubuf[0][to];
            half8 bl = *(const half8*)&Ubuf[1][to];
            half8 ah[2], al[2];
#pragma unroll
            for (int jt = 0; jt < 2; ++jt) {
                int ro = ((jh * 2 + jt) * 16 + l15) * 264 + kc;
                ah[jt] = *(const half8*)&Zh[ro];
                al[jt] = *(const half8*)&Zl[ro];
            }
#pragma unroll
            for (int jt = 0; jt < 2; ++jt) {
                sac[jt] = __builtin_amdgcn_mfma_f32_16x16x32_f16(ah[jt], bh, sac[jt], 0, 0, 0);
                sac[jt] = __builtin_amdgcn_mfma_f32_16x16x32_f16(ah[jt], bl, sac[jt], 0, 0, 0);
                sac[jt] = __builtin_amdgcn_mfma_f32_16x16x32_f16(al[jt], bh, sac[jt], 0, 0, 0);
            }
        }
        __builtin_amdgcn_s_setprio(0);
        float mxh = -1e30f;
#pragma unroll
        for (int jt = 0; jt < 2; ++jt)
#pragma unroll
            for (int r = 0; r < 4; ++r) { sv[jt][r] = sac[jt][r]; mxh = fmaxf(mxh, sv[jt][r]); }
        mxh = fmaxf(mxh, __shfl_xor(mxh, 16));
        mxh = fmaxf(mxh, __shfl_xor(mxh, 32));
        float sumh = 0.f;
#pragma unroll
        for (int jt = 0; jt < 2; ++jt)
#pragma unroll
            for (int r = 0; r < 4; ++r) { float e = expf(sv[jt][r] - mxh); sv[jt][r] = e; sumh += e; }
        sumh += __shfl_xor(sumh, 16);
        sumh += __shfl_xor(sumh, 32);
        if (lq == 0) { Smx[qb][jh][l15] = mxh; Ssum[qb][jh][l15] = sumh; }
    }

    // V band (all waves, 32 cols each)
    f32x4 vac[4][2];
#pragma unroll
    for (int mt = 0; mt < 4; ++mt)
#pragma unroll
        for (int nt = 0; nt < 2; ++nt) vac[mt][nt] = (f32x4){0.f, 0.f, 0.f, 0.f};
    __builtin_amdgcn_s_setprio(1);
#pragma unroll 4
    for (int kt = 0; kt < 8; ++kt) {
        int kc = kt * 32 + lq * 8;
        half8 ah[4], al[4], gh[2], gl[2];
#pragma unroll
        for (int mt = 0; mt < 4; ++mt) {
            int ro = (mt * 16 + l15) * 264 + kc;
            ah[mt] = *(const half8*)&Zh[ro];
            al[mt] = *(const half8*)&Zl[ro];
        }
#pragma unroll
        for (int nt = 0; nt < 2; ++nt) {
            size_t go = (size_t)(w * 32 + nt * 16 + l15) * 256 + kc;
            gh[nt] = *(const half8*)(WvTh + go);
            gl[nt] = *(const half8*)(WvTl + go);
        }
#pragma unroll
        for (int mt = 0; mt < 4; ++mt)
#pragma unroll
            for (int nt = 0; nt < 2; ++nt) {
                vac[mt][nt] = __builtin_amdgcn_mfma_f32_16x16x32_f16(ah[mt], gh[nt], vac[mt][nt], 0, 0, 0);
                vac[mt][nt] = __builtin_amdgcn_mfma_f32_16x16x32_f16(ah[mt], gl[nt], vac[mt][nt], 0, 0, 0);
                vac[mt][nt] = __builtin_amdgcn_mfma_f32_16x16x32_f16(al[mt], gh[nt], vac[mt][nt], 0, 0, 0);
            }
    }
    __builtin_amdgcn_s_setprio(0);
    __syncthreads();   // sync 3: S+T reads done, stats visible

    // finalize softmax (online merge) + write P for this wave's j half
    {
        float mx0 = Smx[qb][0][l15], mx1 = Smx[qb][1][l15];
        float gmx = fmaxf(mx0, mx1);
        float ssum = Ssum[qb][0][l15] * expf(mx0 - gmx) + Ssum[qb][1][l15] * expf(mx1 - gmx);
        float pscale = expf(((jh == 0) ? mx0 : mx1) - gmx) / ssum;
#pragma unroll
        for (int jt = 0; jt < 2; ++jt) {
            half4 h4, l4;
#pragma unroll
            for (int r = 0; r < 4; ++r) {
                float pv = sv[jt][r] * pscale;
                half_t hh = (half_t)pv;
                h4[r] = hh;
                l4[r] = (half_t)(pv - (float)hh);
            }
            int po = l15 * 72 + (jh * 2 + jt) * 16 + lq * 4;
            *(half4*)&Pbuf[0][qb][po] = h4;
            *(half4*)&Pbuf[1][qb][po] = l4;
        }
    }

    // VT write
#pragma unroll
    for (int mt = 0; mt < 4; ++mt)
#pragma unroll
        for (int nt = 0; nt < 2; ++nt) {
            int n = w * 32 + nt * 16 + l15;
            int m0 = mt * 16 + lq * 4;
            half4 h4, l4;
#pragma unroll
            for (int r = 0; r < 4; ++r) {
                float v = vac[mt][nt][r];
                half_t h = (half_t)v;
                h4[r] = h; l4[r] = (half_t)(v - (float)h);
            }
            *(half4*)&Ubuf[0][n * 72 + m0] = h4;
            *(half4*)&Ubuf[1][n * 72 + m0] = l4;
        }
    __syncthreads();   // sync 4: VT + P visible

    // ---- phase O
    f32x4 oc[4][2];
#pragma unroll
    for (int mt = 0; mt < 4; ++mt)
#pragma unroll
        for (int nt = 0; nt < 2; ++nt) oc[mt][nt] = (f32x4){0.f, 0.f, 0.f, 0.f};
    __builtin_amdgcn_s_setprio(1);
#pragma unroll
    for (int kt = 0; kt < 2; ++kt) {
        half8 pah[4], pal[4];
#pragma unroll
        for (int mt = 0; mt < 4; ++mt) {
            int po = l15 * 72 + kt * 32 + lq * 8;
            pah[mt] = *(const half8*)&Pbuf[0][mt][po];
            pal[mt] = *(const half8*)&Pbuf[1][mt][po];
        }
#pragma unroll
        for (int nt = 0; nt < 2; ++nt) {
            int n = w * 32 + nt * 16 + l15;
            half8 vbh = *(const half8*)&Ubuf[0][n * 72 + kt * 32 + lq * 8];
            half8 vbl = *(const half8*)&Ubuf[1][n * 72 + kt * 32 + lq * 8];
#pragma unroll
            for (int mt = 0; mt < 4; ++mt) {
                oc[mt][nt] = __builtin_amdgcn_mfma_f32_16x16x32_f16(pah[mt], vbh, oc[mt][nt], 0, 0, 0);
                oc[mt][nt] = __builtin_amdgcn_mfma_f32_16x16x32_f16(pah[mt], vbl, oc[mt][nt], 0, 0, 0);
                oc[mt][nt] = __builtin_amdgcn_mfma_f32_16x16x32_f16(pal[mt], vbh, oc[mt][nt], 0, 0, 0);
            }
        }
    }
    __builtin_amdgcn_s_setprio(0);

    // ---- epilogue: z_out = O + 0.1*x0; zf1 col-means for this wave's band
    float zfs[2] = {0.f, 0.f};
#pragma unroll
    for (int mt = 0; mt < 4; ++mt)
#pragma unroll
        for (int nt = 0; nt < 2; ++nt)
#pragma unroll
            for (int r = 0; r < 4; ++r) {
                int i = mt * 16 + lq * 4 + r;
                int c = w * 32 + nt * 16 + l15;
                int zo = i * 264 + c;
                float x0 = (float)Zh[zo] + (float)Zl[zo];
                float z1 = oc[mt][nt][r] + 0.1f * x0;
                zb[(size_t)i * FF + c] = z1;
                zfs[nt] += z1;
            }
#pragma unroll
    for (int nt = 0; nt < 2; ++nt) {
        zfs[nt] += __shfl_xor(zfs[nt], 16);
        zfs[nt] += __shfl_xor(zfs[nt], 32);
    }
    if (lq == 0) {
#pragma unroll
        for (int nt = 0; nt < 2; ++nt)
            zf1g[b * FF + w * 32 + nt * 16 + l15] = zfs[nt] * (1.f / 64.f);
    }
}

// ---------------------------------------------------------------------------
// Stack step (degenerate) + fused zfWv vec-mat + mag. One block/batch, 256 thr.
__global__ __launch_bounds__(256) void k_stack3(
        const float* __restrict__ zf1,
        const float* __restrict__ ctrl_w, const float* __restrict__ ctrl_b,
        float* __restrict__ sigma, float* __restrict__ mv,
        const float* __restrict__ Wv32m,
        float* __restrict__ readv, float* __restrict__ zf2,
        const float* __restrict__ halt_w, const float* __restrict__ halt_b,
        float* __restrict__ pval,
        const float* __restrict__ z, float* __restrict__ magpart) {
    __shared__ float zf[256];
    __shared__ float g[3];
    __shared__ float rd[256];
    __shared__ float red[256];

    int b = blockIdx.x, tid = threadIdx.x;
    int w = tid >> 6, lane = tid & 63;

    zf[tid] = zf1[b * FF + tid];
    __syncthreads();

    // zfWv[c=tid] = zf1[b] . Wv_mem[:,c]  (coalesced [e][c] stream, exact fp32)
    float zw = 0.f;
#pragma unroll 8
    for (int e = 0; e < 256; ++e) zw += Wv32m[e * 256 + tid] * zf[e];

    if (w < 3) {
        float s = 0.f;
#pragma unroll
        for (int q = 0; q < 4; ++q) {
            int c = lane + 64 * q;
            s += zf[c] * ctrl_w[c * 3 + w];
        }
#pragma unroll
        for (int off = 1; off < 64; off <<= 1) s += __shfl_xor(s, off);
        if (lane == 0) g[w] = 1.f / (1.f + expf(-(s + ctrl_b[w])));
    }
    __syncthreads();
    float tot = g[0] + g[1] + g[2] + 1e-6f;
    float push = g[0] / tot, pop = g[1] / tot, stay = g[2] / tot;
    float signew = sigma[b] * (push + pop + stay);   // sum(ptr) recurrence
    if (tid == 0) sigma[b] = signew;

    // mv recurrence (all 16 stack slots identical -> single row state)
    float omp = 1.f - push;
    float m2v = mv[b * FF + tid] * omp + push * zw;
    mv[b * FF + tid] = m2v;

    // read = sigma * mv ; zf2 ; pval
    float a = signew * m2v;
    rd[tid] = a;
    readv[b * FF + tid] = a;
    float z2 = zf[tid] + 0.1f * a;
    zf2[b * FF + tid] = z2;
    red[tid] = z2 * halt_w[tid];
    __syncthreads();
    for (int off = 128; off > 0; off >>= 1) {
        if (tid < off) red[tid] += red[tid + off];
        __syncthreads();
    }
    if (tid == 0) pval[b] = 1.f / (1.f + expf(-(red[0] + halt_b[0])));
    __syncthreads();

    // mag sweep over z1 (+0.1*read)
    {
        int d = tid & 127, hf = tid >> 7;
        float rr = 0.1f * rd[d];
        float ri = 0.1f * rd[DD + d];
        const float* zb = z + (size_t)b * (SS * FF);
        float ms = 0.f, msq = 0.f;
        for (int s32 = 0; s32 < 32; ++s32) {
            int s = hf * 32 + s32;
            float zr = zb[s * FF + d] + rr;
            float zi = zb[s * FF + DD + d] + ri;
            float m2 = zr * zr + zi * zi;
            ms += sqrtf(m2); msq += m2;
        }
        red[tid] = ms;
        __syncthreads();
        for (int off = 128; off > 0; off >>= 1) {
            if (tid < off) red[tid] += red[tid + off];
            __syncthreads();
        }
        float tms = red[0];
        __syncthreads();
        red[tid] = msq;
        __syncthreads();
        for (int off = 128; off > 0; off >>= 1) {
            if (tid < off) red[tid] += red[tid + off];
            __syncthreads();
        }
        if (tid == 0) { magpart[2 * b] = tms; magpart[2 * b + 1] = red[0]; }
    }
}

// ---------------------------------------------------------------------------
// Lean VQ kernel; when last!=0 also performs the final ACT accumulation.
__global__ __launch_bounds__(256) void k_vq2(
        const float* __restrict__ zf2g, const float* __restrict__ readv,
        float* __restrict__ probs, float* __restrict__ halt,
        const float* __restrict__ pvalg, const float* __restrict__ magp,
        const float* __restrict__ cb, const float* __restrict__ cb2,
        const float* __restrict__ adj,
        float* __restrict__ delta, float* __restrict__ wact,
        const float* __restrict__ z, float* __restrict__ acc,
        int t, int last) {
    __shared__ float zf[256];
    __shared__ float pr[128];
    __shared__ float upred[8];
    __shared__ float zzred[4];
    __shared__ float mxred[4];
    __shared__ float sered[4];
    __shared__ float waS[1];

    int b = blockIdx.x, tid = threadIdx.x;
    int w = tid >> 6, lane = tid & 63;

    zf[tid] = zf2g[b * FF + tid];

    float up = 0.f;
    if (t > 0) {
        f32x4 mv4 = *(const f32x4*)(magp + tid * 4);
        float pa = mv4[0] + mv4[2];
        float pb = mv4[1] + mv4[3];
#pragma unroll
        for (int off = 1; off < 64; off <<= 1) {
            pa += __shfl_xor(pa, off);
            pb += __shfl_xor(pb, off);
        }
        if (lane == 0) { upred[w * 2] = pa; upred[w * 2 + 1] = pb; }
    }
    __syncthreads();
    if (t > 0) {
        float tms  = upred[0] + upred[2] + upred[4] + upred[6];
        float tmsq = upred[1] + upred[3] + upred[5] + upred[7];
        const float N = 4194304.f;   // B*S*D
        float mean = tms / N;
        float var = tmsq / N - mean * mean;
        float x = var / (1.f + 1e-6f);
        up = (x > 20.f) ? x : log1pf(expf(x));
    }

    {
        float part = zf[tid] * zf[tid];
#pragma unroll
        for (int off = 1; off < 64; off <<= 1) part += __shfl_xor(part, off);
        if (lane == 0) zzred[w] = part;
    }
    __syncthreads();
    float zz = zzred[0] + zzred[1] + zzred[2] + zzred[3];

    int n = tid >> 1, half = tid & 1;
    float dacc = 0.f;
    {
        const float* cbn = cb + n * FF + half * 128;
        const float* zfp = zf + half * 128;
#pragma unroll 8
        for (int c2 = 0; c2 < 128; c2 += 4) {
            f32x4 cv = *(const f32x4*)(cbn + c2);
            dacc += cv[0] * zfp[c2] + cv[1] * zfp[c2 + 1] + cv[2] * zfp[c2 + 2] + cv[3] * zfp[c2 + 3];
        }
        dacc += __shfl_xor(dacc, 1);
    }
    float gacc = 0.f;
    if (t > 0) {
        const float* pp = probs + b * NSYM;
        for (int k = half * 64; k < half * 64 + 64; ++k)
            gacc += pp[k] * adj[k * NSYM + n];
        gacc += __shfl_xor(gacc, 1);
    }

    float dist = (zz + cb2[n] - 2.f * dacc) * (1.f / 256.f);
    float dtot = dist;
    if (t > 0) dtot = dist - 0.01f * up * (1.f / (1.f + expf(-gacc)));
    float vval = -dtot;   // TEMP = 1

    {
        float m = vval;
#pragma unroll
        for (int off = 1; off < 64; off <<= 1) m = fmaxf(m, __shfl_xor(m, off));
        if (lane == 0) mxred[w] = m;
    }
    __syncthreads();
    float mx = fmaxf(fmaxf(mxred[0], mxred[1]), fmaxf(mxred[2], mxred[3]));

    float e = expf(vval - mx);
    {
        float s = (half == 0) ? e : 0.f;
#pragma unroll
        for (int off = 1; off < 64; off <<= 1) s += __shfl_xor(s, off);
        if (lane == 0) sered[w] = s;
    }
    __syncthreads();
    float se = sered[0] + sered[1] + sered[2] + sered[3];
    float psm = e / se;
    if (half == 0) {
        pr[n] = psm;
        probs[b * NSYM + n] = psm;
    }
    __syncthreads();

    float q = 0.f;
#pragma unroll 4
    for (int k = 0; k < NSYM; ++k) q += pr[k] * cb[k * FF + tid];
    float dltc = readv[b * FF + tid] + q;
    delta[b * FF + tid] = dltc;

    if (tid == 0) {
        float h = halt[b], p = pvalg[b];
        float running = (h < 0.99f) ? 1.f : 0.f;
        float w2 = (((h + p * running) >= 0.99f) ? (1.f - h) : p) * running;
        halt[b] = h + w2;
        wact[b] = w2;
        waS[0] = w2;
    }

    if (last) {
        __syncthreads();
        float wa = waS[0];
        if (wa != 0.0f) {
            const float* zb = z + (size_t)b * (SS * FF);
            float* ab = acc + (size_t)b * (SS * FF);
            for (int s = 0; s < SS; ++s)
                ab[s * FF + tid] += wa * (zb[s * FF + tid] + 0.1f * dltc);
        }
    }
}

// ---------------------------------------------------------------------------
extern "C" void kernel_launch(void* const* d_in, const int* in_sizes, int n_in,
                              void* d_out, int out_size, void* d_ws, size_t ws_size,
                              hipStream_t stream) {
    const float* z_real  = (const float*)d_in[0];
    const float* z_imag  = (const float*)d_in[1];
    const float* attn_wr = (const float*)d_in[2];
    const float* attn_wi = (const float*)d_in[3];
    const float* mem_wr  = (const float*)d_in[4];
    const float* mem_wi  = (const float*)d_in[5];
    const float* ctrl_w  = (const float*)d_in[6];
    const float* ctrl_b  = (const float*)d_in[7];
    const float* halt_w  = (const float*)d_in[8];
    const float* halt_b  = (const float*)d_in[9];
    const float* codebook  = (const float*)d_in[10];
    const float* adjacency = (const float*)d_in[11];

    float* ws = (float*)d_ws;
    float* z      = ws + Z_OFF;
    float* WT32   = ws + QKV_OFF;
    half_t* GTh   = (half_t*)(ws + QKV_OFF + 196608);
    half_t* GTl   = GTh + 65536;
    half_t* WvTh  = GTl + 65536;
    half_t* WvTl  = WvTh + 65536;
    float* Wv32m  = ws + WVM_OFF;
    float* mv     = ws + MV_OFF;
    float* sigma  = ws + SIG_OFF;
    float* zf1    = ws + ZF1_OFF;
    float* zf2    = ws + ZF2_OFF;
    float* readv  = ws + READ_OFF;
    float* probs  = ws + PROBS_OFF;
    float* delta  = ws + DELTA_OFF;
    float* halt   = ws + HALT_OFF;
    float* pval   = ws + PVAL_OFF;
    float* wact   = ws + WACT_OFF;
    float* magp   = ws + MAGP_OFF;
    float* cb2    = ws + CB2_OFF;
    float* acc    = (float*)d_out;

    k_buildwt32<<<768, 256, 0, stream>>>(attn_wr, attn_wi, WT32);
    k_buildG<<<256, 256, 0, stream>>>(WT32, GTh, GTl);
    k_splitWv<<<256, 256, 0, stream>>>(WT32, WvTh, WvTl);
    k_buildWv32m<<<256, 256, 0, stream>>>(mem_wr, mem_wi, Wv32m);
    k_cb2<<<1, 128, 0, stream>>>(codebook, cb2);
    k_init<<<32768, 256, 0, stream>>>(z_real, z_imag, z, mv, sigma, halt, acc,
                                      delta, wact);

    for (int t = 0; t < NDEPTH; ++t) {
        k_attn8<<<BB, 512, 0, stream>>>(z, GTh, GTl, WvTh, WvTl, delta, wact, acc, zf1);
        k_stack3<<<BB, 256, 0, stream>>>(zf1, ctrl_w, ctrl_b, sigma, mv, Wv32m,
                                         readv, zf2, halt_w, halt_b, pval, z, magp);
        k_vq2<<<BB, 256, 0, stream>>>(zf2, readv, probs, halt, pval, magp,
                                      codebook, cb2, adjacency, delta, wact,
                                      z, acc, t, (t == NDEPTH - 1) ? 1 : 0);
    }
}

// Round 16
// 784.694 us; speedup vs baseline: 1.0203x; 1.0021x over previous
//
#include <hip/hip_runtime.h>
#include <math.h>

// Problem constants
#define BB 512
#define SS 64
#define DD 128
#define FF 256   // 2D
#define NSYM 128
#define STK 16
#define NDEPTH 8

typedef _Float16 half_t;
typedef __attribute__((ext_vector_type(4))) _Float16 half4;
typedef __attribute__((ext_vector_type(8))) _Float16 half8;
typedef __attribute__((ext_vector_type(4))) float f32x4;

// Workspace offsets (in floats)
#define Z_OFF      0ull                    // B*S*F      = 8388608
#define QKV_OFF    8388608ull              // WT32 + GT/WvT split planes (attn)
#define WVM_OFF    33554432ull             // Wv32m [e][c] = 65536
#define MV_OFF     35651584ull             // mv state B*256 = 131072
#define SIG_OFF    35782656ull             // sigma B = 512
#define ZF1_OFF    41951232ull             // B*256      = 131072
#define ZF2_OFF    42082304ull             // B*256      = 131072
#define READ_OFF   42213376ull             // B*256      = 131072
#define PROBS_OFF  42344448ull             // B*128      = 65536
#define DELTA_OFF  42409984ull             // B*256      = 131072 (read + quant)
#define HALT_OFF   42541056ull             // B          = 512
#define PVAL_OFF   42541568ull             // B          = 512
#define WACT_OFF   42542080ull             // B          = 512
#define MAGP_OFF   42542592ull             // B*2        = 1024
#define CB2_OFF    42936832ull             // 128

// ---------------------------------------------------------------------------
// Combined transposed weight, fp32: WT32[col=h*256+c][e] = W_h[e][c]
__global__ void k_buildwt32(const float* __restrict__ wr, const float* __restrict__ wi,
                            float* __restrict__ WT32) {
    int idx = blockIdx.x * 256 + threadIdx.x;   // 196608 total, grid=768
    if (idx >= 768 * 256) return;
    int col = idx >> 8;
    int e   = idx & 255;
    int h   = col >> 8;
    int c   = col & 255;
    const float* Wr = wr + h * DD * DD;
    const float* Wi = wi + h * DD * DD;
    float v;
    if (c < DD) {
        v = (e < DD) ? Wr[c * DD + e] : -Wi[c * DD + (e - DD)];
    } else {
        int j = c - DD;
        v = (e < DD) ? Wi[j * DD + e] : Wr[j * DD + (e - DD)];
    }
    WT32[idx] = v;
}

// GT[n][e] = G[e][n] = sum_c Wq[e][c]*Wk[n][c], split to fp16 h/l (unscaled).
__global__ __launch_bounds__(256) void k_buildG(const float* __restrict__ WT32,
                                                half_t* __restrict__ GTh,
                                                half_t* __restrict__ GTl) {
    __shared__ float kcol[256];
    int n = blockIdx.x;
    int e = threadIdx.x;
    kcol[e] = WT32[65536 + e * 256 + n];   // Wk[n][c=e]
    __syncthreads();
    float s = 0.f;
    for (int c = 0; c < 256; ++c) s += kcol[c] * WT32[c * 256 + e];  // Wq[e][c]
    half_t h = (half_t)s;
    GTh[n * 256 + e] = h;
    GTl[n * 256 + e] = (half_t)(s - (float)h);
}

// Split the attn V-head columns (cols 512..767 of WT32) to fp16 h/l (transposed).
__global__ void k_splitWv(const float* __restrict__ WT32,
                          half_t* __restrict__ WvTh, half_t* __restrict__ WvTl) {
    int idx = blockIdx.x * 256 + threadIdx.x;   // 65536, grid 256
    float v = WT32[131072 + idx];   // WvT[n][e]
    half_t h = (half_t)v;
    WvTh[idx] = h;
    WvTl[idx] = (half_t)(v - (float)h);
}

// Mem-path V weight in [e][c] fp32 layout (c contiguous -> coalesced dots).
__global__ void k_buildWv32m(const float* __restrict__ wr, const float* __restrict__ wi,
                             float* __restrict__ Wv32m) {
    int idx = blockIdx.x * 256 + threadIdx.x;   // 65536, grid 256
    int e = idx >> 8;
    int c = idx & 255;
    const float* Wr = wr + 2 * DD * DD;   // V head
    const float* Wi = wi + 2 * DD * DD;
    float v;
    if (c < DD) {
        v = (e < DD) ? Wr[c * DD + e] : -Wi[c * DD + (e - DD)];
    } else {
        int j = c - DD;
        v = (e < DD) ? Wi[j * DD + e] : Wr[j * DD + (e - DD)];
    }
    Wv32m[idx] = v;
}

__global__ void k_cb2(const float* __restrict__ cb, float* __restrict__ cb2) {
    int n = threadIdx.x;   // 128 threads
    float s = 0.f;
    for (int c = 0; c < FF; ++c) { float v = cb[n * FF + c]; s += v * v; }
    cb2[n] = s;
}

__global__ __launch_bounds__(256) void k_init(const float* __restrict__ zr_in,
                                              const float* __restrict__ zi_in,
                                              float* __restrict__ z, float* __restrict__ mv,
                                              float* __restrict__ sigma,
                                              float* __restrict__ halt, float* __restrict__ acc,
                                              float* __restrict__ delta, float* __restrict__ wact) {
    size_t idx = (size_t)blockIdx.x * 256 + threadIdx.x;  // grid 32768 -> 8388608
    int c = (int)(idx & 255);
    size_t bs = idx >> 8;
    z[idx] = (c < DD) ? zr_in[bs * DD + c] : zi_in[bs * DD + (c - DD)];
    acc[idx] = 0.f;
    if (idx < 131072) { mv[idx] = 0.f; delta[idx] = 0.f; }
    if (idx < 512)   { halt[idx] = 0.f; wact[idx] = 0.f; sigma[idx] = 1.f; }
}

// ---------------------------------------------------------------------------
// Fused attention step. 8 waves, 1 blk/CU.
// R13 body + cross-barrier prefetch: G frags (kt 0-3) loaded before phase 0,
// Wv frags (kt 0-3) loaded during phase T. Math order identical.
__global__ __launch_bounds__(512, 1) void k_attn8(
        float* __restrict__ z,
        const half_t* __restrict__ GTh, const half_t* __restrict__ GTl,
        const half_t* __restrict__ WvTh, const half_t* __restrict__ WvTl,
        const float* __restrict__ delta, const float* __restrict__ wact,
        float* __restrict__ acc, float* __restrict__ zf1g) {
    __shared__ half_t Zh[16896];         // 64 x 264, 33 KB
    __shared__ half_t Zl[16896];
    __shared__ half_t Ubuf[2][18432];    // union: T[64][264] / VT[256][72]
    __shared__ half_t Pbuf[2][4][1152];
    __shared__ float Smx[4][2][16];      // per-query partial softmax stats
    __shared__ float Ssum[4][2][16];

    int b = blockIdx.x, tid = threadIdx.x;
    int w = tid >> 6, lane = tid & 63;
    int l15 = lane & 15, lq = lane >> 4;
    float* zb = z + (size_t)b * (SS * FF);
    float* accb = acc + (size_t)b * (SS * FF);

    // ---- prefetch G fragments for kt 0-3 (independent of Z; overlaps phase 0 + sync1)
    half8 ghp[4][2], glp[4][2];
#pragma unroll
    for (int kt = 0; kt < 4; ++kt)
#pragma unroll
        for (int nt = 0; nt < 2; ++nt) {
            size_t go = (size_t)(w * 32 + nt * 16 + l15) * 256 + kt * 32 + lq * 8;
            ghp[kt][nt] = *(const half8*)(GTh + go);
            glp[kt][nt] = *(const half8*)(GTl + go);
        }

    // ---- phase 0: x0 = z + 0.1*delta; deferred acc; split to LDS
    float wa = wact[b];
    f32x4 dv = *(const f32x4*)(delta + b * FF + lane * 4);
    bool doacc = (wa != 0.0f);
#pragma unroll
    for (int it = 0; it < 8; ++it) {
        int i = w * 8 + it;
        f32x4 zv = *(const f32x4*)(zb + (size_t)i * FF + lane * 4);
        f32x4 x0;
#pragma unroll
        for (int jj = 0; jj < 4; ++jj) x0[jj] = zv[jj] + 0.1f * dv[jj];
        if (doacc) {
            f32x4 av = *(const f32x4*)(accb + (size_t)i * FF + lane * 4);
#pragma unroll
            for (int jj = 0; jj < 4; ++jj) av[jj] += wa * x0[jj];
            *(f32x4*)(accb + (size_t)i * FF + lane * 4) = av;
        }
        half4 h4, l4;
#pragma unroll
        for (int jj = 0; jj < 4; ++jj) {
            half_t h = (half_t)x0[jj];
            h4[jj] = h; l4[jj] = (half_t)(x0[jj] - (float)h);
        }
        *(half4*)&Zh[i * 264 + lane * 4] = h4;
        *(half4*)&Zl[i * 264 + lane * 4] = l4;
    }
    __syncthreads();   // sync 1: Z staged

    // ---- phase T: T = x0 @ G, wave w owns 32-col band.
    half8 vhp[4][2], vlp[4][2];   // Wv prefetch (issued mid-phase)
    {
        f32x4 tac[4][2];
#pragma unroll
        for (int mt = 0; mt < 4; ++mt)
#pragma unroll
            for (int nt = 0; nt < 2; ++nt) tac[mt][nt] = (f32x4){0.f, 0.f, 0.f, 0.f};
        __builtin_amdgcn_s_setprio(1);
        // kt 0-3: G from prefetched regs
#pragma unroll
        for (int kt = 0; kt < 4; ++kt) {
            int kc = kt * 32 + lq * 8;
            half8 ah[4], al[4];
#pragma unroll
            for (int mt = 0; mt < 4; ++mt) {
                int ro = (mt * 16 + l15) * 264 + kc;
                ah[mt] = *(const half8*)&Zh[ro];
                al[mt] = *(const half8*)&Zl[ro];
            }
#pragma unroll
            for (int mt = 0; mt < 4; ++mt)
#pragma unroll
                for (int nt = 0; nt < 2; ++nt) {
                    tac[mt][nt] = __builtin_amdgcn_mfma_f32_16x16x32_f16(ah[mt], ghp[kt][nt], tac[mt][nt], 0, 0, 0);
                    tac[mt][nt] = __builtin_amdgcn_mfma_f32_16x16x32_f16(ah[mt], glp[kt][nt], tac[mt][nt], 0, 0, 0);
                    tac[mt][nt] = __builtin_amdgcn_mfma_f32_16x16x32_f16(al[mt], ghp[kt][nt], tac[mt][nt], 0, 0, 0);
                }
        }
        // prefetch Wv kt 0-3 (overlaps remaining T MFMAs + sync2 + S phase)
#pragma unroll
        for (int kt = 0; kt < 4; ++kt)
#pragma unroll
            for (int nt = 0; nt < 2; ++nt) {
                size_t go = (size_t)(w * 32 + nt * 16 + l15) * 256 + kt * 32 + lq * 8;
                vhp[kt][nt] = *(const half8*)(WvTh + go);
                vlp[kt][nt] = *(const half8*)(WvTl + go);
            }
        // kt 4-7: G loaded in-loop
#pragma unroll
        for (int kt = 4; kt < 8; ++kt) {
            int kc = kt * 32 + lq * 8;
            half8 ah[4], al[4], gh[2], gl[2];
#pragma unroll
            for (int mt = 0; mt < 4; ++mt) {
                int ro = (mt * 16 + l15) * 264 + kc;
                ah[mt] = *(const half8*)&Zh[ro];
                al[mt] = *(const half8*)&Zl[ro];
            }
#pragma unroll
            for (int nt = 0; nt < 2; ++nt) {
                size_t go = (size_t)(w * 32 + nt * 16 + l15) * 256 + kc;
                gh[nt] = *(const half8*)(GTh + go);
                gl[nt] = *(const half8*)(GTl + go);
            }
#pragma unroll
            for (int mt = 0; mt < 4; ++mt)
#pragma unroll
                for (int nt = 0; nt < 2; ++nt) {
                    tac[mt][nt] = __builtin_amdgcn_mfma_f32_16x16x32_f16(ah[mt], gh[nt], tac[mt][nt], 0, 0, 0);
                    tac[mt][nt] = __builtin_amdgcn_mfma_f32_16x16x32_f16(ah[mt], gl[nt], tac[mt][nt], 0, 0, 0);
                    tac[mt][nt] = __builtin_amdgcn_mfma_f32_16x16x32_f16(al[mt], gh[nt], tac[mt][nt], 0, 0, 0);
                }
        }
        __builtin_amdgcn_s_setprio(0);
        const float scale = 0.08838834764831845f;
#pragma unroll
        for (int mt = 0; mt < 4; ++mt)
#pragma unroll
            for (int nt = 0; nt < 2; ++nt)
#pragma unroll
                for (int r = 0; r < 4; ++r) {
                    int m = mt * 16 + lq * 4 + r;
                    int n = w * 32 + nt * 16 + l15;
                    float v = tac[mt][nt][r] * scale;
                    half_t h = (half_t)v;
                    Ubuf[0][m * 264 + n] = h;
                    Ubuf[1][m * 264 + n] = (half_t)(v - (float)h);
                }
    }
    __syncthreads();   // sync 2: T ready

    // ---- phase B: all 8 waves: S half (48 MFMA) -> partial stats; then V band.
    int qb = w & 3;    // query band
    int jh = w >> 2;   // j half
    float sv[2][4];
    {
        f32x4 sac[2];
        sac[0] = (f32x4){0.f, 0.f, 0.f, 0.f};
        sac[1] = (f32x4){0.f, 0.f, 0.f, 0.f};
        __builtin_amdgcn_s_setprio(1);
#pragma unroll 2
        for (int kt = 0; kt < 8; ++kt) {
            int kc = kt * 32 + lq * 8;
            int to = (qb * 16 + l15) * 264 + kc;
            half8 bh = *(const half8*)&Ubuf[0][to];
            half8 bl = *(const half8*)&Ubuf[1][to];
            half8 ah[2], al[2];
#pragma unroll
            for (int jt = 0; jt < 2; ++jt) {
                int ro = ((jh * 2 + jt) * 16 + l15) * 264 + kc;
                ah[jt] = *(const half8*)&Zh[ro];
                al[jt] = *(const half8*)&Zl[ro];
            }
#pragma unroll
            for (int jt = 0; jt < 2; ++jt) {
                sac[jt] = __builtin_amdgcn_mfma_f32_16x16x32_f16(ah[jt], bh, sac[jt], 0, 0, 0);
                sac[jt] = __builtin_amdgcn_mfma_f32_16x16x32_f16(ah[jt], bl, sac[jt], 0, 0, 0);
                sac[jt] = __builtin_amdgcn_mfma_f32_16x16x32_f16(al[jt], bh, sac[jt], 0, 0, 0);
            }
        }
        __builtin_amdgcn_s_setprio(0);
        float mxh = -1e30f;
#pragma unroll
        for (int jt = 0; jt < 2; ++jt)
#pragma unroll
            for (int r = 0; r < 4; ++r) { sv[jt][r] = sac[jt][r]; mxh = fmaxf(mxh, sv[jt][r]); }
        mxh = fmaxf(mxh, __shfl_xor(mxh, 16));
        mxh = fmaxf(mxh, __shfl_xor(mxh, 32));
        float sumh = 0.f;
#pragma unroll
        for (int jt = 0; jt < 2; ++jt)
#pragma unroll
            for (int r = 0; r < 4; ++r) { float e = expf(sv[jt][r] - mxh); sv[jt][r] = e; sumh += e; }
        sumh += __shfl_xor(sumh, 16);
        sumh += __shfl_xor(sumh, 32);
        if (lq == 0) { Smx[qb][jh][l15] = mxh; Ssum[qb][jh][l15] = sumh; }
    }

    // V band (all waves, 32 cols each); kt 0-3 use prefetched Wv frags
    f32x4 vac[4][2];
#pragma unroll
    for (int mt = 0; mt < 4; ++mt)
#pragma unroll
        for (int nt = 0; nt < 2; ++nt) vac[mt][nt] = (f32x4){0.f, 0.f, 0.f, 0.f};
    __builtin_amdgcn_s_setprio(1);
#pragma unroll
    for (int kt = 0; kt < 4; ++kt) {
        int kc = kt * 32 + lq * 8;
        half8 ah[4], al[4];
#pragma unroll
        for (int mt = 0; mt < 4; ++mt) {
            int ro = (mt * 16 + l15) * 264 + kc;
            ah[mt] = *(const half8*)&Zh[ro];
            al[mt] = *(const half8*)&Zl[ro];
        }
#pragma unroll
        for (int mt = 0; mt < 4; ++mt)
#pragma unroll
            for (int nt = 0; nt < 2; ++nt) {
                vac[mt][nt] = __builtin_amdgcn_mfma_f32_16x16x32_f16(ah[mt], vhp[kt][nt], vac[mt][nt], 0, 0, 0);
                vac[mt][nt] = __builtin_amdgcn_mfma_f32_16x16x32_f16(ah[mt], vlp[kt][nt], vac[mt][nt], 0, 0, 0);
                vac[mt][nt] = __builtin_amdgcn_mfma_f32_16x16x32_f16(al[mt], vhp[kt][nt], vac[mt][nt], 0, 0, 0);
            }
    }
#pragma unroll
    for (int kt = 4; kt < 8; ++kt) {
        int kc = kt * 32 + lq * 8;
        half8 ah[4], al[4], gh[2], gl[2];
#pragma unroll
        for (int mt = 0; mt < 4; ++mt) {
            int ro = (mt * 16 + l15) * 264 + kc;
            ah[mt] = *(const half8*)&Zh[ro];
            al[mt] = *(const half8*)&Zl[ro];
        }
#pragma unroll
        for (int nt = 0; nt < 2; ++nt) {
            size_t go = (size_t)(w * 32 + nt * 16 + l15) * 256 + kc;
            gh[nt] = *(const half8*)(WvTh + go);
            gl[nt] = *(const half8*)(WvTl + go);
        }
#pragma unroll
        for (int mt = 0; mt < 4; ++mt)
#pragma unroll
            for (int nt = 0; nt < 2; ++nt) {
                vac[mt][nt] = __builtin_amdgcn_mfma_f32_16x16x32_f16(ah[mt], gh[nt], vac[mt][nt], 0, 0, 0);
                vac[mt][nt] = __builtin_amdgcn_mfma_f32_16x16x32_f16(ah[mt], gl[nt], vac[mt][nt], 0, 0, 0);
                vac[mt][nt] = __builtin_amdgcn_mfma_f32_16x16x32_f16(al[mt], gh[nt], vac[mt][nt], 0, 0, 0);
            }
    }
    __builtin_amdgcn_s_setprio(0);
    __syncthreads();   // sync 3: S+T reads done, stats visible

    // finalize softmax (online merge) + write P for this wave's j half
    {
        float mx0 = Smx[qb][0][l15], mx1 = Smx[qb][1][l15];
        float gmx = fmaxf(mx0, mx1);
        float ssum = Ssum[qb][0][l15] * expf(mx0 - gmx) + Ssum[qb][1][l15] * expf(mx1 - gmx);
        float pscale = expf(((jh == 0) ? mx0 : mx1) - gmx) / ssum;
#pragma unroll
        for (int jt = 0; jt < 2; ++jt) {
            half4 h4, l4;
#pragma unroll
            for (int r = 0; r < 4; ++r) {
                float pv = sv[jt][r] * pscale;
                half_t hh = (half_t)pv;
                h4[r] = hh;
                l4[r] = (half_t)(pv - (float)hh);
            }
            int po = l15 * 72 + (jh * 2 + jt) * 16 + lq * 4;
            *(half4*)&Pbuf[0][qb][po] = h4;
            *(half4*)&Pbuf[1][qb][po] = l4;
        }
    }

    // VT write
#pragma unroll
    for (int mt = 0; mt < 4; ++mt)
#pragma unroll
        for (int nt = 0; nt < 2; ++nt) {
            int n = w * 32 + nt * 16 + l15;
            int m0 = mt * 16 + lq * 4;
            half4 h4, l4;
#pragma unroll
            for (int r = 0; r < 4; ++r) {
                float v = vac[mt][nt][r];
                half_t h = (half_t)v;
                h4[r] = h; l4[r] = (half_t)(v - (float)h);
            }
            *(half4*)&Ubuf[0][n * 72 + m0] = h4;
            *(half4*)&Ubuf[1][n * 72 + m0] = l4;
        }
    __syncthreads();   // sync 4: VT + P visible

    // ---- phase O
    f32x4 oc[4][2];
#pragma unroll
    for (int mt = 0; mt < 4; ++mt)
#pragma unroll
        for (int nt = 0; nt < 2; ++nt) oc[mt][nt] = (f32x4){0.f, 0.f, 0.f, 0.f};
    __builtin_amdgcn_s_setprio(1);
#pragma unroll
    for (int kt = 0; kt < 2; ++kt) {
        half8 pah[4], pal[4];
#pragma unroll
        for (int mt = 0; mt < 4; ++mt) {
            int po = l15 * 72 + kt * 32 + lq * 8;
            pah[mt] = *(const half8*)&Pbuf[0][mt][po];
            pal[mt] = *(const half8*)&Pbuf[1][mt][po];
        }
#pragma unroll
        for (int nt = 0; nt < 2; ++nt) {
            int n = w * 32 + nt * 16 + l15;
            half8 vbh = *(const half8*)&Ubuf[0][n * 72 + kt * 32 + lq * 8];
            half8 vbl = *(const half8*)&Ubuf[1][n * 72 + kt * 32 + lq * 8];
#pragma unroll
            for (int mt = 0; mt < 4; ++mt) {
                oc[mt][nt] = __builtin_amdgcn_mfma_f32_16x16x32_f16(pah[mt], vbh, oc[mt][nt], 0, 0, 0);
                oc[mt][nt] = __builtin_amdgcn_mfma_f32_16x16x32_f16(pah[mt], vbl, oc[mt][nt], 0, 0, 0);
                oc[mt][nt] = __builtin_amdgcn_mfma_f32_16x16x32_f16(pal[mt], vbh, oc[mt][nt], 0, 0, 0);
            }
        }
    }
    __builtin_amdgcn_s_setprio(0);

    // ---- epilogue: z_out = O + 0.1*x0; zf1 col-means for this wave's band
    float zfs[2] = {0.f, 0.f};
#pragma unroll
    for (int mt = 0; mt < 4; ++mt)
#pragma unroll
        for (int nt = 0; nt < 2; ++nt)
#pragma unroll
            for (int r = 0; r < 4; ++r) {
                int i = mt * 16 + lq * 4 + r;
                int c = w * 32 + nt * 16 + l15;
                int zo = i * 264 + c;
                float x0 = (float)Zh[zo] + (float)Zl[zo];
                float z1 = oc[mt][nt][r] + 0.1f * x0;
                zb[(size_t)i * FF + c] = z1;
                zfs[nt] += z1;
            }
#pragma unroll
    for (int nt = 0; nt < 2; ++nt) {
        zfs[nt] += __shfl_xor(zfs[nt], 16);
        zfs[nt] += __shfl_xor(zfs[nt], 32);
    }
    if (lq == 0) {
#pragma unroll
        for (int nt = 0; nt < 2; ++nt)
            zf1g[b * FF + w * 32 + nt * 16 + l15] = zfs[nt] * (1.f / 64.f);
    }
}

// ---------------------------------------------------------------------------
// Stack step (degenerate) + fused zfWv vec-mat + mag. One block/batch, 256 thr.
__global__ __launch_bounds__(256) void k_stack3(
        const float* __restrict__ zf1,
        const float* __restrict__ ctrl_w, const float* __restrict__ ctrl_b,
        float* __restrict__ sigma, float* __restrict__ mv,
        const float* __restrict__ Wv32m,
        float* __restrict__ readv, float* __restrict__ zf2,
        const float* __restrict__ halt_w, const float* __restrict__ halt_b,
        float* __restrict__ pval,
        const float* __restrict__ z, float* __restrict__ magpart) {
    __shared__ float zf[256];
    __shared__ float g[3];
    __shared__ float rd[256];
    __shared__ float red[256];

    int b = blockIdx.x, tid = threadIdx.x;
    int w = tid >> 6, lane = tid & 63;

    zf[tid] = zf1[b * FF + tid];
    __syncthreads();

    // zfWv[c=tid] = zf1[b] . Wv_mem[:,c]  (coalesced [e][c] stream, exact fp32)
    float zw = 0.f;
#pragma unroll 8
    for (int e = 0; e < 256; ++e) zw += Wv32m[e * 256 + tid] * zf[e];

    if (w < 3) {
        float s = 0.f;
#pragma unroll
        for (int q = 0; q < 4; ++q) {
            int c = lane + 64 * q;
            s += zf[c] * ctrl_w[c * 3 + w];
        }
#pragma unroll
        for (int off = 1; off < 64; off <<= 1) s += __shfl_xor(s, off);
        if (lane == 0) g[w] = 1.f / (1.f + expf(-(s + ctrl_b[w])));
    }
    __syncthreads();
    float tot = g[0] + g[1] + g[2] + 1e-6f;
    float push = g[0] / tot, pop = g[1] / tot, stay = g[2] / tot;
    float signew = sigma[b] * (push + pop + stay);   // sum(ptr) recurrence
    if (tid == 0) sigma[b] = signew;

    // mv recurrence (all 16 stack slots identical -> single row state)
    float omp = 1.f - push;
    float m2v = mv[b * FF + tid] * omp + push * zw;
    mv[b * FF + tid] = m2v;

    // read = sigma * mv ; zf2 ; pval
    float a = signew * m2v;
    rd[tid] = a;
    readv[b * FF + tid] = a;
    float z2 = zf[tid] + 0.1f * a;
    zf2[b * FF + tid] = z2;
    red[tid] = z2 * halt_w[tid];
    __syncthreads();
    for (int off = 128; off > 0; off >>= 1) {
        if (tid < off) red[tid] += red[tid + off];
        __syncthreads();
    }
    if (tid == 0) pval[b] = 1.f / (1.f + expf(-(red[0] + halt_b[0])));
    __syncthreads();

    // mag sweep over z1 (+0.1*read)
    {
        int d = tid & 127, hf = tid >> 7;
        float rr = 0.1f * rd[d];
        float ri = 0.1f * rd[DD + d];
        const float* zb = z + (size_t)b * (SS * FF);
        float ms = 0.f, msq = 0.f;
        for (int s32 = 0; s32 < 32; ++s32) {
            int s = hf * 32 + s32;
            float zr = zb[s * FF + d] + rr;
            float zi = zb[s * FF + DD + d] + ri;
            float m2 = zr * zr + zi * zi;
            ms += sqrtf(m2); msq += m2;
        }
        red[tid] = ms;
        __syncthreads();
        for (int off = 128; off > 0; off >>= 1) {
            if (tid < off) red[tid] += red[tid + off];
            __syncthreads();
        }
        float tms = red[0];
        __syncthreads();
        red[tid] = msq;
        __syncthreads();
        for (int off = 128; off > 0; off >>= 1) {
            if (tid < off) red[tid] += red[tid + off];
            __syncthreads();
        }
        if (tid == 0) { magpart[2 * b] = tms; magpart[2 * b + 1] = red[0]; }
    }
}

// ---------------------------------------------------------------------------
// Lean VQ kernel; when last!=0 also performs the final ACT accumulation.
__global__ __launch_bounds__(256) void k_vq2(
        const float* __restrict__ zf2g, const float* __restrict__ readv,
        float* __restrict__ probs, float* __restrict__ halt,
        const float* __restrict__ pvalg, const float* __restrict__ magp,
        const float* __restrict__ cb, const float* __restrict__ cb2,
        const float* __restrict__ adj,
        float* __restrict__ delta, float* __restrict__ wact,
        const float* __restrict__ z, float* __restrict__ acc,
        int t, int last) {
    __shared__ float zf[256];
    __shared__ float pr[128];
    __shared__ float upred[8];
    __shared__ float zzred[4];
    __shared__ float mxred[4];
    __shared__ float sered[4];
    __shared__ float waS[1];

    int b = blockIdx.x, tid = threadIdx.x;
    int w = tid >> 6, lane = tid & 63;

    zf[tid] = zf2g[b * FF + tid];

    float up = 0.f;
    if (t > 0) {
        f32x4 mv4 = *(const f32x4*)(magp + tid * 4);
        float pa = mv4[0] + mv4[2];
        float pb = mv4[1] + mv4[3];
#pragma unroll
        for (int off = 1; off < 64; off <<= 1) {
            pa += __shfl_xor(pa, off);
            pb += __shfl_xor(pb, off);
        }
        if (lane == 0) { upred[w * 2] = pa; upred[w * 2 + 1] = pb; }
    }
    __syncthreads();
    if (t > 0) {
        float tms  = upred[0] + upred[2] + upred[4] + upred[6];
        float tmsq = upred[1] + upred[3] + upred[5] + upred[7];
        const float N = 4194304.f;   // B*S*D
        float mean = tms / N;
        float var = tmsq / N - mean * mean;
        float x = var / (1.f + 1e-6f);
        up = (x > 20.f) ? x : log1pf(expf(x));
    }

    {
        float part = zf[tid] * zf[tid];
#pragma unroll
        for (int off = 1; off < 64; off <<= 1) part += __shfl_xor(part, off);
        if (lane == 0) zzred[w] = part;
    }
    __syncthreads();
    float zz = zzred[0] + zzred[1] + zzred[2] + zzred[3];

    int n = tid >> 1, half = tid & 1;
    float dacc = 0.f;
    {
        const float* cbn = cb + n * FF + half * 128;
        const float* zfp = zf + half * 128;
#pragma unroll 8
        for (int c2 = 0; c2 < 128; c2 += 4) {
            f32x4 cv = *(const f32x4*)(cbn + c2);
            dacc += cv[0] * zfp[c2] + cv[1] * zfp[c2 + 1] + cv[2] * zfp[c2 + 2] + cv[3] * zfp[c2 + 3];
        }
        dacc += __shfl_xor(dacc, 1);
    }
    float gacc = 0.f;
    if (t > 0) {
        const float* pp = probs + b * NSYM;
        for (int k = half * 64; k < half * 64 + 64; ++k)
            gacc += pp[k] * adj[k * NSYM + n];
        gacc += __shfl_xor(gacc, 1);
    }

    float dist = (zz + cb2[n] - 2.f * dacc) * (1.f / 256.f);
    float dtot = dist;
    if (t > 0) dtot = dist - 0.01f * up * (1.f / (1.f + expf(-gacc)));
    float vval = -dtot;   // TEMP = 1

    {
        float m = vval;
#pragma unroll
        for (int off = 1; off < 64; off <<= 1) m = fmaxf(m, __shfl_xor(m, off));
        if (lane == 0) mxred[w] = m;
    }
    __syncthreads();
    float mx = fmaxf(fmaxf(mxred[0], mxred[1]), fmaxf(mxred[2], mxred[3]));

    float e = expf(vval - mx);
    {
        float s = (half == 0) ? e : 0.f;
#pragma unroll
        for (int off = 1; off < 64; off <<= 1) s += __shfl_xor(s, off);
        if (lane == 0) sered[w] = s;
    }
    __syncthreads();
    float se = sered[0] + sered[1] + sered[2] + sered[3];
    float psm = e / se;
    if (half == 0) {
        pr[n] = psm;
        probs[b * NSYM + n] = psm;
    }
    __syncthreads();

    float q = 0.f;
#pragma unroll 4
    for (int k = 0; k < NSYM; ++k) q += pr[k] * cb[k * FF + tid];
    float dltc = readv[b * FF + tid] + q;
    delta[b * FF + tid] = dltc;

    if (tid == 0) {
        float h = halt[b], p = pvalg[b];
        float running = (h < 0.99f) ? 1.f : 0.f;
        float w2 = (((h + p * running) >= 0.99f) ? (1.f - h) : p) * running;
        halt[b] = h + w2;
        wact[b] = w2;
        waS[0] = w2;
    }

    if (last) {
        __syncthreads();
        float wa = waS[0];
        if (wa != 0.0f) {
            const float* zb = z + (size_t)b * (SS * FF);
            float* ab = acc + (size_t)b * (SS * FF);
            for (int s = 0; s < SS; ++s)
                ab[s * FF + tid] += wa * (zb[s * FF + tid] + 0.1f * dltc);
        }
    }
}

// ---------------------------------------------------------------------------
extern "C" void kernel_launch(void* const* d_in, const int* in_sizes, int n_in,
                              void* d_out, int out_size, void* d_ws, size_t ws_size,
                              hipStream_t stream) {
    const float* z_real  = (const float*)d_in[0];
    const float* z_imag  = (const float*)d_in[1];
    const float* attn_wr = (const float*)d_in[2];
    const float* attn_wi = (const float*)d_in[3];
    const float* mem_wr  = (const float*)d_in[4];
    const float* mem_wi  = (const float*)d_in[5];
    const float* ctrl_w  = (const float*)d_in[6];
    const float* ctrl_b  = (const float*)d_in[7];
    const float* halt_w  = (const float*)d_in[8];
    const float* halt_b  = (const float*)d_in[9];
    const float* codebook  = (const float*)d_in[10];
    const float* adjacency = (const float*)d_in[11];

    float* ws = (float*)d_ws;
    float* z      = ws + Z_OFF;
    float* WT32   = ws + QKV_OFF;
    half_t* GTh   = (half_t*)(ws + QKV_OFF + 196608);
    half_t* GTl   = GTh + 65536;
    half_t* WvTh  = GTl + 65536;
    half_t* WvTl  = WvTh + 65536;
    float* Wv32m  = ws + WVM_OFF;
    float* mv     = ws + MV_OFF;
    float* sigma  = ws + SIG_OFF;
    float* zf1    = ws + ZF1_OFF;
    float* zf2    = ws + ZF2_OFF;
    float* readv  = ws + READ_OFF;
    float* probs  = ws + PROBS_OFF;
    float* delta  = ws + DELTA_OFF;
    float* halt   = ws + HALT_OFF;
    float* pval   = ws + PVAL_OFF;
    float* wact   = ws + WACT_OFF;
    float* magp   = ws + MAGP_OFF;
    float* cb2    = ws + CB2_OFF;
    float* acc    = (float*)d_out;

    k_buildwt32<<<768, 256, 0, stream>>>(attn_wr, attn_wi, WT32);
    k_buildG<<<256, 256, 0, stream>>>(WT32, GTh, GTl);
    k_splitWv<<<256, 256, 0, stream>>>(WT32, WvTh, WvTl);
    k_buildWv32m<<<256, 256, 0, stream>>>(mem_wr, mem_wi, Wv32m);
    k_cb2<<<1, 128, 0, stream>>>(codebook, cb2);
    k_init<<<32768, 256, 0, stream>>>(z_real, z_imag, z, mv, sigma, halt, acc,
                                      delta, wact);

    for (int t = 0; t < NDEPTH; ++t) {
        k_attn8<<<BB, 512, 0, stream>>>(z, GTh, GTl, WvTh, WvTl, delta, wact, acc, zf1);
        k_stack3<<<BB, 256, 0, stream>>>(zf1, ctrl_w, ctrl_b, sigma, mv, Wv32m,
                                         readv, zf2, halt_w, halt_b, pval, z, magp);
        k_vq2<<<BB, 256, 0, stream>>>(zf2, readv, probs, halt, pval, magp,
                                      codebook, cb2, adjacency, delta, wact,
                                      z, acc, t, (t == NDEPTH - 1) ? 1 : 0);
    }
}